// Round 4
// baseline (1572.709 us; speedup 1.0000x reference)
//
#include <hip/hip_runtime.h>

#define VV 50257
#define DD 50
#define TT 1024
#define BB 1024

__device__ __forceinline__ float rl(float v, int lane) {
    return __int_as_float(__builtin_amdgcn_readlane(__float_as_int(v), lane));
}
__device__ __forceinline__ float sigmf(float x) { return 1.0f / (1.0f + __expf(-x)); }
__device__ __forceinline__ float tanhf_fast(float x) {
    float e = __expf(-2.0f * fabsf(x));
    return copysignf((1.0f - e) / (1.0f + e), x);
}

// P1[v][j] = b1[0][j] + sum_d emb[v][d] * kx1[d][j]   (one-time, ~0.5 GFLOP)
__global__ void proj_emb(const float* __restrict__ emb, const float* __restrict__ kx1,
                         const float* __restrict__ b1, float* __restrict__ P1) {
    int j = threadIdx.x;             // 0..95
    int v0 = blockIdx.x * 8;
    #pragma unroll 1
    for (int vv = 0; vv < 8; ++vv) {
        int v = v0 + vv;
        if (v >= VV) return;
        float acc = b1[j];
        #pragma unroll
        for (int d = 0; d < DD; ++d)
            acc += emb[v * DD + d] * kx1[d * 96 + j];
        P1[v * 96 + j] = acc;
    }
}

// Two waves per block, TWO rows per block, one barrier per step.
//  Wave A (wv=0): GRU2 recurrence, rows r0,r1. Pre-barrier: m(t)=h2(t-1)·kh2+b2[1]
//    (2 rows -> 2x independent FMA chains per readlane). Post-barrier: read x(t)
//    from ring slot t&3, gates -> h2(t).
//  Wave B (wv=1): GRU1 + input projection, rows r0,r1, one step ahead.
//    Pre-barrier: prefetch P1(t+2), GRU1 recurrence+gates -> h1(t+1).
//    Post-barrier: x(t+1)=h1(t+1)·kx2+b2[0] -> ring slot (t+1)&3.
//    (balances the two barrier intervals: A ~550 instr, B ~490.)
//  Ring safety: slot s written at iter s-1(post), read at iter s(post), rewritten
//  at iter s+3(post) with barriers in between.
//  Register budget: ONE unified w[192] array (single live range; role-dependent
//  contents), __launch_bounds__(128,1) -> 512 unified budget so ~235 live floats
//  allocate as architected VGPRs (round-3's (128,2)=256 budget forced 120 arch +
//  AGPR/scratch churn). Per-lane layouts identical to rounds 1/3 (absmax 0).
__global__ __launch_bounds__(128, 1)
void rnn_main(const int* __restrict__ tokens, const float* __restrict__ P1,
              const float* __restrict__ kh1, const float* __restrict__ b1,
              const float* __restrict__ kx2, const float* __restrict__ kh2,
              const float* __restrict__ b2, const float* __restrict__ wg,
              const float* __restrict__ bg, const float* __restrict__ wd,
              const float* __restrict__ bd, float* __restrict__ out) {
    const int lane = threadIdx.x & 63;
    const int wv   = threadIdx.x >> 6;        // 0 = GRU2 wave, 1 = GRU1/proj wave
    const int row0 = blockIdx.x * 2;
    const int row1 = row0 + 1;
    const int l32  = lane & 31;
    const int* __restrict__ trow0 = tokens + row0 * TT;
    const int* __restrict__ trow1 = tokens + row1 * TT;

    __shared__ float4 xb[4][2][64];           // ring of x-triples, 2 rows

    float w[192];
    float f0, f1, f2, f3 = 0.f, f4 = 0.f;     // role-dependent biases

    if (wv == 0) {
        // kh2 columns: z=lane, r=64+lane, h=128+lane, interleaved by k
        #pragma unroll
        for (int k = 0; k < 64; ++k) {
            w[3 * k]     = kh2[k * 192 + lane];
            w[3 * k + 1] = kh2[k * 192 + 64 + lane];
            w[3 * k + 2] = kh2[k * 192 + 128 + lane];
        }
        f0 = b2[192 + lane];                  // recurrent biases b2[1]
        f1 = b2[256 + lane];
        f2 = b2[320 + lane];
    } else {
        // kh1: col lane (z for lane<32, r for lane>=32); h-col 64+lane for lane<32
        // kx2: 3 cols interleaved at w[64..191]
        #pragma unroll
        for (int k = 0; k < 32; ++k) {
            w[k]          = kh1[k * 96 + lane];
            w[32 + k]     = (lane < 32) ? kh1[k * 96 + 64 + lane] : 0.f;
            w[64 + 3 * k] = kx2[k * 192 + lane];
            w[65 + 3 * k] = kx2[k * 192 + 64 + lane];
            w[66 + 3 * k] = kx2[k * 192 + 128 + lane];
        }
        f0 = b1[96 + lane];                   // GRU1 recurrent z/r bias
        f1 = (lane < 32) ? b1[160 + lane] : 0.f;   // GRU1 recurrent h bias
        f2 = b2[lane];                        // input-proj biases b2[0]
        f3 = b2[64 + lane];
        f4 = b2[128 + lane];
    }

    float h1r0 = 0.f, h1r1 = 0.f;             // wave B state (lanes>=32 garbage ok)
    float h2r0 = 0.f, h2r1 = 0.f;             // wave A state
    float pz0 = 0.f, pr0 = 0.f, ph0 = 0.f, pz1 = 0.f, pr1 = 0.f, ph1 = 0.f;
    if (wv == 1) {                            // p-triples for GRU1 step 0
        const float* __restrict__ p0 = P1 + trow0[0] * 96;
        const float* __restrict__ p1 = P1 + trow1[0] * 96;
        pz0 = p0[l32]; pr0 = p0[32 + l32]; ph0 = p0[64 + l32];
        pz1 = p1[l32]; pr1 = p1[32 + l32]; ph1 = p1[64 + l32];
    }

    float mz0, mr0, mh0, mz1, mr1, mh1;

    #pragma unroll 1
    for (int t = -1; t < TT; ++t) {
        // ---------------- pre-barrier ----------------
        if (wv == 0) {
            if (t >= 0) {
                mz0 = f0; mr0 = f1; mh0 = f2; mz1 = f0; mr1 = f1; mh1 = f2;
                #pragma unroll
                for (int k = 0; k < 64; ++k) {
                    float s0 = rl(h2r0, k);
                    float s1 = rl(h2r1, k);
                    mz0 += s0 * w[3 * k];
                    mr0 += s0 * w[3 * k + 1];
                    mh0 += s0 * w[3 * k + 2];
                    mz1 += s1 * w[3 * k];
                    mr1 += s1 * w[3 * k + 1];
                    mh1 += s1 * w[3 * k + 2];
                }
            }
        } else if (t + 1 < TT) {
            // prefetch p(t+2)
            int t2 = (t + 2 < TT) ? (t + 2) : (TT - 1);
            const float* __restrict__ pn0 = P1 + trow0[t2] * 96;
            const float* __restrict__ pn1 = P1 + trow1[t2] * 96;
            float pzn0 = pn0[l32], prn0 = pn0[32 + l32], phn0 = pn0[64 + l32];
            float pzn1 = pn1[l32], prn1 = pn1[32 + l32], phn1 = pn1[64 + l32];
            // GRU1 recurrence: h1(t) -> h1(t+1), both rows
            float az0 = f0, ah0 = f1, az1 = f0, ah1 = f1;
            #pragma unroll
            for (int k = 0; k < 32; ++k) {
                float s0 = rl(h1r0, k);
                float s1 = rl(h1r1, k);
                az0 += s0 * w[k];
                ah0 += s0 * w[32 + k];
                az1 += s1 * w[k];
                ah1 += s1 * w[32 + k];
            }
            float ra0 = __shfl_xor(az0, 32);  // r-preact to lanes 0..31
            float ra1 = __shfl_xor(az1, 32);
            float z0  = sigmf(pz0 + az0);
            float g0  = sigmf(pr0 + ra0);
            float hh0 = tanhf_fast(ph0 + g0 * ah0);
            h1r0 = z0 * h1r0 + (1.f - z0) * hh0;
            float z1  = sigmf(pz1 + az1);
            float g1  = sigmf(pr1 + ra1);
            float hh1 = tanhf_fast(ph1 + g1 * ah1);
            h1r1 = z1 * h1r1 + (1.f - z1) * hh1;
            pz0 = pzn0; pr0 = prn0; ph0 = phn0;
            pz1 = pzn1; pr1 = prn1; ph1 = phn1;
        }
        __syncthreads();
        // ---------------- post-barrier ----------------
        if (wv == 0) {
            if (t >= 0) {
                float4 x0 = xb[t & 3][0][lane];
                float4 x1 = xb[t & 3][1][lane];
                float z0  = sigmf(x0.x + mz0);
                float r0  = sigmf(x0.y + mr0);
                float hh0 = tanhf_fast(x0.z + r0 * mh0);  // reset after recurrent mm
                h2r0 = z0 * h2r0 + (1.f - z0) * hh0;
                float z1  = sigmf(x1.x + mz1);
                float r1  = sigmf(x1.y + mr1);
                float hh1 = tanhf_fast(x1.z + r1 * mh1);
                h2r1 = z1 * h2r1 + (1.f - z1) * hh1;
            }
        } else if (t + 1 < TT) {
            // x(t+1) = h1(t+1)·kx2 + b2[0]  -> ring slot (t+1)&3
            float xz0 = f2, xr0 = f3, xh0 = f4, xz1 = f2, xr1 = f3, xh1 = f4;
            #pragma unroll
            for (int k = 0; k < 32; ++k) {
                float s0 = rl(h1r0, k);
                float s1 = rl(h1r1, k);
                xz0 += s0 * w[64 + 3 * k];
                xr0 += s0 * w[65 + 3 * k];
                xh0 += s0 * w[66 + 3 * k];
                xz1 += s1 * w[64 + 3 * k];
                xr1 += s1 * w[65 + 3 * k];
                xh1 += s1 * w[66 + 3 * k];
            }
            xb[(t + 1) & 3][0][lane] = make_float4(xz0, xr0, xh0, 0.f);
            xb[(t + 1) & 3][1][lane] = make_float4(xz1, xr1, xh1, 0.f);
        }
    }

    // ---- tail: GLU + dense head, wave A only (holds h2 for both rows) ----
    if (wv == 0) {
        float a0 = bg[lane], a1 = bg[64 + lane], a2 = bg[128 + lane], a3 = bg[192 + lane];
        #pragma unroll
        for (int k = 0; k < 64; ++k) {
            float s = rl(h2r0, k);
            a0 += s * wg[k * 256 + lane];
            a1 += s * wg[k * 256 + 64 + lane];
            a2 += s * wg[k * 256 + 128 + lane];
            a3 += s * wg[k * 256 + 192 + lane];
        }
        float g = a0 * sigmf(a2) * wd[lane] + a1 * sigmf(a3) * wd[64 + lane];
        g += __shfl_xor(g, 32); g += __shfl_xor(g, 16); g += __shfl_xor(g, 8);
        g += __shfl_xor(g, 4);  g += __shfl_xor(g, 2);  g += __shfl_xor(g, 1);
        if (lane == 0) out[row0] = sigmf(g + bd[0]);

        float c0 = bg[lane], c1 = bg[64 + lane], c2 = bg[128 + lane], c3 = bg[192 + lane];
        #pragma unroll
        for (int k = 0; k < 64; ++k) {
            float s = rl(h2r1, k);
            c0 += s * wg[k * 256 + lane];
            c1 += s * wg[k * 256 + 64 + lane];
            c2 += s * wg[k * 256 + 128 + lane];
            c3 += s * wg[k * 256 + 192 + lane];
        }
        float g1 = c0 * sigmf(c2) * wd[lane] + c1 * sigmf(c3) * wd[64 + lane];
        g1 += __shfl_xor(g1, 32); g1 += __shfl_xor(g1, 16); g1 += __shfl_xor(g1, 8);
        g1 += __shfl_xor(g1, 4);  g1 += __shfl_xor(g1, 2);  g1 += __shfl_xor(g1, 1);
        if (lane == 0) out[row1] = sigmf(g1 + bd[0]);
    }
}

extern "C" void kernel_launch(void* const* d_in, const int* in_sizes, int n_in,
                              void* d_out, int out_size, void* d_ws, size_t ws_size,
                              hipStream_t stream) {
    const int*   tokens = (const int*)d_in[0];
    const float* emb = (const float*)d_in[1];
    const float* kx1 = (const float*)d_in[2];
    const float* kh1 = (const float*)d_in[3];
    const float* b1  = (const float*)d_in[4];
    const float* kx2 = (const float*)d_in[5];
    const float* kh2 = (const float*)d_in[6];
    const float* b2  = (const float*)d_in[7];
    const float* wg  = (const float*)d_in[8];
    const float* bg  = (const float*)d_in[9];
    const float* wd  = (const float*)d_in[10];
    const float* bd  = (const float*)d_in[11];
    float* out = (float*)d_out;
    float* P1  = (float*)d_ws;   // needs 50257*96*4 = 19.3 MB of workspace

    proj_emb<<<(VV + 7) / 8, 96, 0, stream>>>(emb, kx1, b1, P1);
    rnn_main<<<BB / 2, 128, 0, stream>>>(tokens, P1, kh1, b1, kx2, kh2, b2,
                                         wg, bg, wd, bd, out);
}

// Round 5
// 1303.163 us; speedup vs baseline: 1.2068x; 1.2068x over previous
//
#include <hip/hip_runtime.h>

#define VV 50257
#define DD 50
#define TT 1024
#define BB 1024

__device__ __forceinline__ float rl(float v, int lane) {
    return __int_as_float(__builtin_amdgcn_readlane(__float_as_int(v), lane));
}
__device__ __forceinline__ float sigmf(float x) { return 1.0f / (1.0f + __expf(-x)); }
__device__ __forceinline__ float tanhf_fast(float x) {
    float e = __expf(-2.0f * fabsf(x));
    return copysignf((1.0f - e) / (1.0f + e), x);
}

// P1[v][j] = b1[0][j] + sum_d emb[v][d] * kx1[d][j]   (one-time, ~0.5 GFLOP)
__global__ void proj_emb(const float* __restrict__ emb, const float* __restrict__ kx1,
                         const float* __restrict__ b1, float* __restrict__ P1) {
    int j = threadIdx.x;             // 0..95
    int v0 = blockIdx.x * 8;
    #pragma unroll 1
    for (int vv = 0; vv < 8; ++vv) {
        int v = v0 + vv;
        if (v >= VV) return;
        float acc = b1[j];
        #pragma unroll
        for (int d = 0; d < DD; ++d)
            acc += emb[v * DD + d] * kx1[d * 96 + j];
        P1[v * 96 + j] = acc;
    }
}

// Two waves per block, ONE row per block, one barrier per step.
// Geometry: 1024 blocks x 2 waves = 2048 waves = 2 waves/SIMD (round-3 geometry,
// which hid dep-chain latency), with round-4's clean register regime:
// __launch_bounds__(128,1) -> full unified budget, single w[192] live range,
// VGPR ~240 < 256 so the 512-reg/SIMD file still fits 2 waves (key invariant:
// VGPR_Count must stay <= 256).
//  Wave A (wv=0): GRU2 recurrence. Pre-barrier: m(t)=h2(t-1)·kh2+b2[1].
//    Post-barrier: read x(t) from ring slot t&3, gates -> h2(t).
//  Wave B (wv=1): GRU1 + input projection, one step ahead. Pre-barrier:
//    prefetch P1(t+2), GRU1 recurrence+gates -> h1(t+1). Post-barrier:
//    x(t+1)=h1(t+1)·kx2+b2[0] -> ring slot (t+1)&3 (balances barrier intervals).
//  Ring safety: slot s written post-barrier of iter s-1, read post-barrier of
//  iter s (separated by barrier s), rewritten at iter s+3.
//  Per-lane layouts identical to rounds 1/3/4 (all passed absmax 0).
__global__ __launch_bounds__(128, 1)
void rnn_main(const int* __restrict__ tokens, const float* __restrict__ P1,
              const float* __restrict__ kh1, const float* __restrict__ b1,
              const float* __restrict__ kx2, const float* __restrict__ kh2,
              const float* __restrict__ b2, const float* __restrict__ wg,
              const float* __restrict__ bg, const float* __restrict__ wd,
              const float* __restrict__ bd, float* __restrict__ out) {
    const int lane = threadIdx.x & 63;
    const int wv   = threadIdx.x >> 6;        // 0 = GRU2 wave, 1 = GRU1/proj wave
    const int row  = blockIdx.x;
    const int l32  = lane & 31;
    const int* __restrict__ trow = tokens + row * TT;

    __shared__ float4 xb[4][64];              // ring of x-triples

    float w[192];
    float f0, f1, f2, f3 = 0.f, f4 = 0.f;     // role-dependent biases

    if (wv == 0) {
        // kh2 columns: z=lane, r=64+lane, h=128+lane, interleaved by k
        #pragma unroll
        for (int k = 0; k < 64; ++k) {
            w[3 * k]     = kh2[k * 192 + lane];
            w[3 * k + 1] = kh2[k * 192 + 64 + lane];
            w[3 * k + 2] = kh2[k * 192 + 128 + lane];
        }
        f0 = b2[192 + lane];                  // recurrent biases b2[1]
        f1 = b2[256 + lane];
        f2 = b2[320 + lane];
    } else {
        // kh1: col lane (z for lane<32, r for lane>=32); h-col 64+lane for lane<32
        // kx2: 3 cols interleaved at w[64..191]
        #pragma unroll
        for (int k = 0; k < 32; ++k) {
            w[k]          = kh1[k * 96 + lane];
            w[32 + k]     = (lane < 32) ? kh1[k * 96 + 64 + lane] : 0.f;
            w[64 + 3 * k] = kx2[k * 192 + lane];
            w[65 + 3 * k] = kx2[k * 192 + 64 + lane];
            w[66 + 3 * k] = kx2[k * 192 + 128 + lane];
        }
        f0 = b1[96 + lane];                   // GRU1 recurrent z/r bias
        f1 = (lane < 32) ? b1[160 + lane] : 0.f;   // GRU1 recurrent h bias
        f2 = b2[lane];                        // input-proj biases b2[0]
        f3 = b2[64 + lane];
        f4 = b2[128 + lane];
    }

    float h1 = 0.f, h2 = 0.f;
    float pz = 0.f, pr = 0.f, ph = 0.f;
    if (wv == 1) {                            // p-triple for GRU1 step 0
        const float* __restrict__ p = P1 + trow[0] * 96;
        pz = p[l32]; pr = p[32 + l32]; ph = p[64 + l32];
    }

    float mz, mr, mh;

    #pragma unroll 1
    for (int t = -1; t < TT; ++t) {
        // ---------------- pre-barrier ----------------
        if (wv == 0) {
            if (t >= 0) {
                mz = f0; mr = f1; mh = f2;
                #pragma unroll
                for (int k = 0; k < 64; ++k) {
                    float s = rl(h2, k);
                    mz += s * w[3 * k];
                    mr += s * w[3 * k + 1];
                    mh += s * w[3 * k + 2];
                }
            }
        } else if (t + 1 < TT) {
            // prefetch p(t+2)
            int t2 = (t + 2 < TT) ? (t + 2) : (TT - 1);
            const float* __restrict__ pn = P1 + trow[t2] * 96;
            float pzn = pn[l32], prn = pn[32 + l32], phn = pn[64 + l32];
            // GRU1 recurrence: h1(t) -> h1(t+1)
            float az = f0, ah = f1;
            #pragma unroll
            for (int k = 0; k < 32; ++k) {
                float s = rl(h1, k);
                az += s * w[k];
                ah += s * w[32 + k];
            }
            float ra  = __shfl_xor(az, 32);   // r-preact to lanes 0..31
            float z1  = sigmf(pz + az);
            float g1  = sigmf(pr + ra);
            float hh1 = tanhf_fast(ph + g1 * ah);
            h1 = z1 * h1 + (1.f - z1) * hh1;
            pz = pzn; pr = prn; ph = phn;
        }
        __syncthreads();
        // ---------------- post-barrier ----------------
        if (wv == 0) {
            if (t >= 0) {
                float4 x  = xb[t & 3][lane];
                float z2  = sigmf(x.x + mz);
                float r2  = sigmf(x.y + mr);
                float hh2 = tanhf_fast(x.z + r2 * mh);   // reset after recurrent mm
                h2 = z2 * h2 + (1.f - z2) * hh2;
            }
        } else if (t + 1 < TT) {
            // x(t+1) = h1(t+1)·kx2 + b2[0]  -> ring slot (t+1)&3
            float xz = f2, xr = f3, xh = f4;
            #pragma unroll
            for (int k = 0; k < 32; ++k) {
                float s = rl(h1, k);
                xz += s * w[64 + 3 * k];
                xr += s * w[65 + 3 * k];
                xh += s * w[66 + 3 * k];
            }
            xb[(t + 1) & 3][lane] = make_float4(xz, xr, xh, 0.f);
        }
    }

    // ---- tail: GLU + dense head, wave A only (holds h2) ----
    if (wv == 0) {
        float a0 = bg[lane], a1 = bg[64 + lane], a2 = bg[128 + lane], a3 = bg[192 + lane];
        #pragma unroll
        for (int k = 0; k < 64; ++k) {
            float s = rl(h2, k);
            a0 += s * wg[k * 256 + lane];
            a1 += s * wg[k * 256 + 64 + lane];
            a2 += s * wg[k * 256 + 128 + lane];
            a3 += s * wg[k * 256 + 192 + lane];
        }
        float g = a0 * sigmf(a2) * wd[lane] + a1 * sigmf(a3) * wd[64 + lane];
        g += __shfl_xor(g, 32); g += __shfl_xor(g, 16); g += __shfl_xor(g, 8);
        g += __shfl_xor(g, 4);  g += __shfl_xor(g, 2);  g += __shfl_xor(g, 1);
        if (lane == 0) out[row] = sigmf(g + bd[0]);
    }
}

extern "C" void kernel_launch(void* const* d_in, const int* in_sizes, int n_in,
                              void* d_out, int out_size, void* d_ws, size_t ws_size,
                              hipStream_t stream) {
    const int*   tokens = (const int*)d_in[0];
    const float* emb = (const float*)d_in[1];
    const float* kx1 = (const float*)d_in[2];
    const float* kh1 = (const float*)d_in[3];
    const float* b1  = (const float*)d_in[4];
    const float* kx2 = (const float*)d_in[5];
    const float* kh2 = (const float*)d_in[6];
    const float* b2  = (const float*)d_in[7];
    const float* wg  = (const float*)d_in[8];
    const float* bg  = (const float*)d_in[9];
    const float* wd  = (const float*)d_in[10];
    const float* bd  = (const float*)d_in[11];
    float* out = (float*)d_out;
    float* P1  = (float*)d_ws;   // needs 50257*96*4 = 19.3 MB of workspace

    proj_emb<<<(VV + 7) / 8, 96, 0, stream>>>(emb, kx1, b1, P1);
    rnn_main<<<BB, 128, 0, stream>>>(tokens, P1, kh1, b1, kx2, kh2, b2,
                                     wg, bg, wd, bd, out);
}